// Round 1
// baseline (1252.349 us; speedup 1.0000x reference)
//
#include <hip/hip_runtime.h>
#include <stdint.h>

#define NCLS 80
#define MAXB 150
#define BATCH 16
#define NANCH 25200
#define CAP 4096
#define NE (NCLS * MAXB)  // 12000

typedef unsigned long long u64;
typedef unsigned int u32;

__device__ __forceinline__ float sigm(float x) { return 1.0f / (1.0f + expf(-x)); }

// ---------------- Pass 1: decode boxes + candidate compaction ----------------
__global__ void decode_kernel(const float* __restrict__ fm, int g, float ratio,
                              float a0w, float a0h, float a1w, float a1h,
                              float a2w, float a2h, int nbase,
                              float* __restrict__ boxes_ws,
                              u64* __restrict__ cand_keys,
                              int* __restrict__ cand_cnt) {
  int i = blockIdx.x * blockDim.x + threadIdx.x;
  int per_img = g * g * 3;
  if (i >= BATCH * per_img) return;
  int b = i / per_img;
  int r = i - b * per_img;
  int cell = r / 3, a = r - cell * 3;
  int y = cell / g, x = cell - y * g;
  const float* p = fm + (size_t)(b * g * g + cell) * 255 + a * 85;
  float tx = p[0], ty = p[1], tw = p[2], th = p[3], tc = p[4];
  float aw = (a == 0) ? a0w : ((a == 1) ? a1w : a2w);
  float ah = (a == 0) ? a0h : ((a == 1) ? a1h : a2h);
  float cx = (sigm(tx) + (float)x) * ratio;
  float cy = (sigm(ty) + (float)y) * ratio;
  float w = expf(tw) * aw;
  float hh = expf(th) * ah;
  int n = nbase + cell * 3 + a;
  float4 bx = make_float4(cx - w * 0.5f, cy - hh * 0.5f,
                          cx + w * 0.5f, cy + hh * 0.5f);
  reinterpret_cast<float4*>(boxes_ws)[(size_t)b * NANCH + n] = bx;
  float cs = sigm(tc);
  // score = cs*ps <= cs in fp32, so cs > 0.9 is an exact-safe necessary condition
  if (cs > 0.9f) {
    for (int c = 0; c < NCLS; ++c) {
      float pl = p[5 + c];
      if (pl > 2.19f) {  // conservative pre-cull: need sigm(pl) > 0.9 -> pl > 2.1972
        float s = cs * sigm(pl);
        if (s > 0.9f) {
          int bc = b * NCLS + c;
          int pos = atomicAdd(&cand_cnt[bc], 1);
          if (pos < CAP) {
            // key: high = score bits (positive float -> monotone), low = ~idx
            // descending sort => score desc, lowest anchor idx first on ties
            cand_keys[(size_t)bc * CAP + pos] =
                ((u64)__float_as_uint(s) << 32) | (u32)(0xFFFFFFFFu - (u32)n);
          }
        }
      }
    }
  }
}

// ---------------- Pass 2: per-(image,class) top-150 + greedy NMS ----------------
__global__ __launch_bounds__(256) void nms_kernel(
    const u64* __restrict__ cand_keys, const int* __restrict__ cand_cnt,
    const float* __restrict__ boxes_ws,
    float* __restrict__ fs, int* __restrict__ fi) {
  __shared__ u64 sk[CAP];
  __shared__ float4 sbox[MAXB];
  __shared__ float sarea[MAXB];
  __shared__ float sscore[MAXB];
  __shared__ int sidx[MAXB];
  __shared__ unsigned char svalid[MAXB];
  __shared__ unsigned char ssup[MAXB];
  int bc = blockIdx.x;
  int b = bc / NCLS;
  int tid = threadIdx.x;
  int count = cand_cnt[bc];
  if (count > CAP) count = CAP;
  const u64* src = cand_keys + (size_t)bc * CAP;
  for (int i = tid; i < CAP; i += 256) sk[i] = (i < count) ? src[i] : 0ull;
  __syncthreads();
  // bitonic sort, descending (u64 keys; zeros sink to the end)
  for (int k = 2; k <= CAP; k <<= 1) {
    for (int j = k >> 1; j > 0; j >>= 1) {
      for (int i = tid; i < CAP; i += 256) {
        int ixj = i ^ j;
        if (ixj > i) {
          u64 va = sk[i], vb = sk[ixj];
          if (((i & k) == 0) ? (va < vb) : (va > vb)) { sk[i] = vb; sk[ixj] = va; }
        }
      }
      __syncthreads();
    }
  }
  if (tid < MAXB) {
    bool v = tid < count;
    float sc = -1.0f;
    int n = 0;
    float4 bx = make_float4(0.f, 0.f, 0.f, 0.f);
    if (v) {
      u64 key = sk[tid];
      sc = __uint_as_float((u32)(key >> 32));
      n = (int)(0xFFFFFFFFu - (u32)(key & 0xFFFFFFFFu));
      bx = reinterpret_cast<const float4*>(boxes_ws)[(size_t)b * NANCH + n];
    }
    sbox[tid] = bx;
    sarea[tid] = (bx.z - bx.x) * (bx.w - bx.y);
    sscore[tid] = sc;
    sidx[tid] = n;
    svalid[tid] = v ? 1 : 0;
    ssup[tid] = 0;
  }
  __syncthreads();
  float4 mybox = make_float4(0.f, 0.f, 0.f, 0.f);
  float myarea = 0.f;
  if (tid < MAXB) { mybox = sbox[tid]; myarea = sarea[tid]; }
  // greedy scan: keep_i = valid[i] && !sup[i]; suppress j>i with IoU > 0.1.
  // sup[i] can only be set by iterations < i, so the scan order is exact.
  for (int i = 0; i < MAXB - 1; ++i) {
    if (svalid[i] && !ssup[i]) {  // uniform LDS broadcast read
      if (tid > i && tid < MAXB) {
        float ltx = fmaxf(sbox[i].x, mybox.x);
        float lty = fmaxf(sbox[i].y, mybox.y);
        float rbx = fminf(sbox[i].z, mybox.z);
        float rby = fminf(sbox[i].w, mybox.w);
        float iw = fmaxf(rbx - ltx, 0.f);
        float ih = fmaxf(rby - lty, 0.f);
        float inter = iw * ih;
        float iou = inter / (sarea[i] + myarea - inter + 1e-9f);  // ref op order
        if (iou > 0.1f) ssup[tid] = 1;
      }
    }
    __syncthreads();
  }
  if (tid < MAXB) {
    bool keep = svalid[tid] && !ssup[tid];
    fs[(size_t)bc * MAXB + tid] = keep ? sscore[tid] : -1.0f;
    fi[(size_t)bc * MAXB + tid] = sidx[tid];
  }
}

// ---------------- Pass 3: per-image top-150 across classes ----------------
__global__ __launch_bounds__(1024) void topk_kernel(
    const float* __restrict__ fs, const int* __restrict__ fi,
    const float* __restrict__ boxes_ws, float* __restrict__ out) {
  __shared__ u64 keys[NE];   // 96 KB (gfx950: 160 KB/WG allowed)
  __shared__ u64 wmax[16];
  __shared__ u64 swin;
  int b = blockIdx.x, tid = threadIdx.x;
  for (int e = tid; e < NE; e += 1024) {
    float v = fs[(size_t)b * NE + e];
    u32 u = __float_as_uint(v);
    u = (u & 0x80000000u) ? ~u : (u | 0x80000000u);  // monotone float map
    keys[e] = ((u64)u << 32) | (u32)(0xFFFFFFFFu - (u32)e);  // ties: lower e first
  }
  __syncthreads();
  float* ob = out;                      // [B][150][4]
  float* osc = out + BATCH * MAXB * 4;  // [B][150]
  float* olb = out + BATCH * MAXB * 5;  // [B][150] labels as float
  for (int r = 0; r < MAXB; ++r) {
    u64 lm = 0;
    int lpos = -1;
    for (int e = tid; e < NE; e += 1024) {
      u64 kk = keys[e];
      if (kk > lm) { lm = kk; lpos = e; }
    }
    u64 m = lm;
    for (int off = 32; off > 0; off >>= 1) {
      u64 o = __shfl_xor(m, off);
      if (o > m) m = o;
    }
    if ((tid & 63) == 0) wmax[tid >> 6] = m;
    __syncthreads();
    if (tid == 0) {
      u64 wbest = wmax[0];
      for (int i = 1; i < 16; ++i) if (wmax[i] > wbest) wbest = wmax[i];
      swin = wbest;
    }
    __syncthreads();
    u64 w = swin;
    if (lm == w) {  // unique owner (keys unique, nonzero)
      keys[lpos] = 0;
      u32 e = 0xFFFFFFFFu - (u32)(w & 0xFFFFFFFFu);
      u32 mu = (u32)(w >> 32);
      float x1, y1, x2, y2, sc, lab;
      if (mu > 0x80000000u) {  // fs > 0 -> kept entry
        sc = __uint_as_float(mu & 0x7FFFFFFFu);
        int c = e / MAXB, k = e - c * MAXB;
        int idx = fi[((size_t)b * NCLS + c) * MAXB + k];
        float4 bx = reinterpret_cast<const float4*>(boxes_ws)[(size_t)b * NANCH + idx];
        x1 = bx.x; y1 = bx.y; x2 = bx.z; y2 = bx.w;
        lab = (float)c;
      } else {
        x1 = y1 = x2 = y2 = -1.f; sc = -1.f; lab = -1.f;
      }
      float* q = ob + ((size_t)b * MAXB + r) * 4;
      q[0] = x1; q[1] = y1; q[2] = x2; q[3] = y2;
      osc[(size_t)b * MAXB + r] = sc;
      olb[(size_t)b * MAXB + r] = lab;
    }
    __syncthreads();  // winner-clear visible before next round
  }
}

extern "C" void kernel_launch(void* const* d_in, const int* in_sizes, int n_in,
                              void* d_out, int out_size, void* d_ws, size_t ws_size,
                              hipStream_t stream) {
  (void)in_sizes; (void)n_in; (void)out_size; (void)ws_size;
  const float* p0 = (const float*)d_in[0];  // [16,20,20,255]
  const float* p1 = (const float*)d_in[1];  // [16,40,40,255]
  const float* p2 = (const float*)d_in[2];  // [16,80,80,255]
  char* ws = (char*)d_ws;
  // ws layout (bytes):
  float* boxes_ws = (float*)ws;                       // 16*25200*4 f32 = 6,451,200
  int* cand_cnt = (int*)(ws + 6451200);               // 1280 i32    -> 6,456,320
  u64* cand_keys = (u64*)(ws + 6456320);              // 1280*4096 u64 -> 48,399,360
  float* fs = (float*)(ws + 48399360);                // 1280*150 f32 -> 49,167,360
  int* fi = (int*)(ws + 49167360);                    // 1280*150 i32 -> 49,935,360

  hipMemsetAsync(cand_cnt, 0, NCLS * BATCH * sizeof(int), stream);

  // level order matches reference concat: p0 (anchors[6:9]), p1 (anchors[3:6]), p2 (anchors[0:3])
  int t0 = BATCH * 20 * 20 * 3;
  decode_kernel<<<(t0 + 255) / 256, 256, 0, stream>>>(
      p0, 20, 32.f, 116.f, 90.f, 156.f, 198.f, 373.f, 326.f, 0,
      boxes_ws, cand_keys, cand_cnt);
  int t1 = BATCH * 40 * 40 * 3;
  decode_kernel<<<(t1 + 255) / 256, 256, 0, stream>>>(
      p1, 40, 16.f, 30.f, 61.f, 62.f, 45.f, 59.f, 119.f, 1200,
      boxes_ws, cand_keys, cand_cnt);
  int t2 = BATCH * 80 * 80 * 3;
  decode_kernel<<<(t2 + 255) / 256, 256, 0, stream>>>(
      p2, 80, 8.f, 10.f, 13.f, 16.f, 30.f, 33.f, 23.f, 6000,
      boxes_ws, cand_keys, cand_cnt);

  nms_kernel<<<BATCH * NCLS, 256, 0, stream>>>(cand_keys, cand_cnt, boxes_ws, fs, fi);
  topk_kernel<<<BATCH, 1024, 0, stream>>>(fs, fi, boxes_ws, (float*)d_out);
}